// Round 2
// baseline (481.247 us; speedup 1.0000x reference)
//
#include <hip/hip_runtime.h>
#include <stdint.h>

// GhostAttention on MI355X (gfx950).
// B=2, T=2048, C=2048, H=16, hd=128.
// Pipeline: convert -> QKV proj GEMMs (bf16 MFMA, fp32 accum; Q,K stored as
// hi/lo bf16 pairs for fp32-accurate scores) -> V transpose -> causal
// relu-attention with linear normalizer (hi/lo split QK^T) -> out GEMM (fp32).

typedef unsigned short u16;
typedef __bf16 bf16x8 __attribute__((ext_vector_type(8)));
typedef float floatx4 __attribute__((ext_vector_type(4)));
typedef unsigned short ushort8_t __attribute__((ext_vector_type(8)));

__device__ __forceinline__ u16 f2bf(float f) {
  unsigned int u = __builtin_bit_cast(unsigned int, f);
  u += 0x7FFFu + ((u >> 16) & 1u);   // round-to-nearest-even
  return (u16)(u >> 16);
}
__device__ __forceinline__ float bf2f(u16 h) {
  unsigned int u = ((unsigned int)h) << 16;
  return __builtin_bit_cast(float, u);
}

__device__ __forceinline__ bf16x8 ld_frag(const u16* p) {
  return __builtin_bit_cast(bf16x8, *(const ushort8_t*)p);
}

// XOR-swizzled LDS offset: tile row length R elements (R%8==0), cprMask = R/8-1.
__device__ __forceinline__ int swz(int row, int col, int R, int cprMask) {
  int chunk = ((col >> 3) ^ row) & cprMask;
  return row * R + chunk * 8 + (col & 7);
}

__device__ __forceinline__ void async_copy16(const void* g, void* l) {
  __builtin_amdgcn_global_load_lds(
      (const __attribute__((address_space(1))) void*)g,
      (__attribute__((address_space(3))) void*)l, 16, 0, 0);
}

// Stage rows x R (bf16) tile from global (row stride grs elements) into swizzled LDS.
template<int R, int NINST>
__device__ __forceinline__ void stage_swz(const u16* g, size_t grs, u16* lds, int tid) {
  constexpr int CPR = R / 8;
  #pragma unroll
  for (int i = 0; i < NINST; ++i) {
    int f = tid + i * 256;                 // 16B chunk index in LDS
    int row = f / CPR;
    int sc = f & (CPR - 1);                // stored chunk position
    int c = sc ^ (row & (CPR - 1));        // logical chunk
    async_copy16(g + (size_t)row * grs + c * 8, (char*)lds + f * 16);
  }
}

// ---------------------------------------------------------------- converts
__global__ void f32_to_bf16_kernel(const float* __restrict__ in, u16* __restrict__ out, int n) {
  int i = (blockIdx.x * blockDim.x + threadIdx.x) * 4;
  if (i < n) {
    float4 v = *(const float4*)(in + i);
    ushort4 o;
    o.x = f2bf(v.x); o.y = f2bf(v.y); o.z = f2bf(v.z); o.w = f2bf(v.w);
    *(ushort4*)(out + i) = o;
  }
}

// ---------------------------------------------------------------- GEMM (B^T)
// C[M,N] = A[M,K] @ B[N,K]^T, bf16 in, fp32 accum.
// MODE 0: bf16 head-major [B,H,T,128]
// MODE 1: fp32 row-major [M,N]
// MODE 2: head-major hi/lo bf16 pair (C=hi, C2=lo)  -- fp32-accurate storage
template<int MODE>
__global__ __launch_bounds__(256, 2) void gemm_bt(
    const u16* __restrict__ A, const u16* __restrict__ B,
    void* __restrict__ C, void* __restrict__ C2,
    const int M, const int N, const int K)
{
  __shared__ __align__(16) u16 As[128 * 32];
  __shared__ __align__(16) u16 Bs[128 * 32];
  const int tid = threadIdx.x;
  const int w = tid >> 6, lane = tid & 63, lr = lane & 15, lq = lane >> 4;
  const int bn0 = blockIdx.x * 128, bm0 = blockIdx.y * 128;
  const int wm = (w >> 1) * 64, wn = (w & 1) * 64;
  floatx4 acc[4][4] = {};
  const u16* Ab = A + (size_t)bm0 * K;
  const u16* Bb = B + (size_t)bn0 * K;

  for (int k0 = 0; k0 < K; k0 += 32) {
    __syncthreads();
    stage_swz<32, 2>(Ab + k0, K, As, tid);
    stage_swz<32, 2>(Bb + k0, K, Bs, tid);
    __syncthreads();
    bf16x8 af[4], bfr[4];
    #pragma unroll
    for (int t = 0; t < 4; ++t) {
      af[t]  = ld_frag(&As[swz(wm + t * 16 + lr, lq * 8, 32, 3)]);
      bfr[t] = ld_frag(&Bs[swz(wn + t * 16 + lr, lq * 8, 32, 3)]);
    }
    #pragma unroll
    for (int mt = 0; mt < 4; ++mt)
      #pragma unroll
      for (int nt = 0; nt < 4; ++nt)
        acc[mt][nt] = __builtin_amdgcn_mfma_f32_16x16x32_bf16(af[mt], bfr[nt], acc[mt][nt], 0, 0, 0);
  }

  // epilogue: C/D layout col=lane&15, row=(lane>>4)*4+reg
  #pragma unroll
  for (int mt = 0; mt < 4; ++mt) {
    #pragma unroll
    for (int nt = 0; nt < 4; ++nt) {
      #pragma unroll
      for (int r = 0; r < 4; ++r) {
        const int m = bm0 + wm + mt * 16 + lq * 4 + r;
        const int n = bn0 + wn + nt * 16 + lr;
        const float v = acc[mt][nt][r];
        if (MODE == 1) {
          ((float*)C)[(size_t)m * N + n] = v;
        } else {
          const int bb = m >> 11, t = m & 2047, h = n >> 7, d = n & 127;
          const size_t idx = (((size_t)(bb * 16 + h) * 2048) + t) * 128 + d;
          const u16 hi = f2bf(v);
          ((u16*)C)[idx] = hi;
          if (MODE == 2) ((u16*)C2)[idx] = f2bf(v - bf2f(hi));
        }
      }
    }
  }
}

// ---------------------------------------------------------------- V transpose
// Vh [BH, T=2048, 128] -> Vt [BH, 128, T=2048]
__global__ void transpose_v(const u16* __restrict__ Vh, u16* __restrict__ Vt) {
  __shared__ u16 tile[64][65];
  const int bh = blockIdx.x, t0 = blockIdx.y * 64, d0 = blockIdx.z * 64;
  const int tid = threadIdx.x;
  const u16* src = Vh + ((size_t)bh * 2048 + t0) * 128 + d0;
  #pragma unroll
  for (int i = 0; i < 16; ++i) {
    int e = tid + i * 256;
    int r = e >> 6, c = e & 63;
    tile[r][c] = src[(size_t)r * 128 + c];
  }
  __syncthreads();
  u16* dst = Vt + ((size_t)bh * 128 + d0) * 2048 + t0;
  #pragma unroll
  for (int i = 0; i < 16; ++i) {
    int e = tid + i * 256;
    int r = e >> 6, c = e & 63;            // r = d index, c = t index
    dst[(size_t)r * 2048 + c] = tile[c][r];
  }
}

// ---------------------------------------------------------------- attention
// Per block: one (bh, q-tile of 128). K-tiles of 64. out = (P@V)/(P@1 + eps),
// P = relu(S*scale + 0.1) with causal mask. Scores via hi/lo bf16 split:
// s = qhi*khi + qlo*khi + qhi*klo  (fp32-accurate, residual ~2^-18).
__global__ __launch_bounds__(256, 2) void attn_kernel(
    const u16* __restrict__ Qhi, const u16* __restrict__ Qlo,
    const u16* __restrict__ Khi, const u16* __restrict__ Klo,
    const u16* __restrict__ Vt, u16* __restrict__ Ob)
{
  __shared__ __align__(16) u16 smem[32768];   // 64 KB
  u16* Ks   = smem;            // [64][128]  swz cpr 16
  u16* Kslo = smem + 8192;     // [64][128]
  u16* Vts  = smem + 16384;    // [128][64]  swz cpr 8
  u16* Ps   = smem + 24576;    // [128][64]
  const int tid = threadIdx.x;
  const int w = tid >> 6, lane = tid & 63, lr = lane & 15, lq = lane >> 4;
  const int bh = blockIdx.x;
  const int qt = (int)gridDim.y - 1 - (int)blockIdx.y;  // heavy tiles first
  const int q0 = qt * 128;
  const size_t bhT = (size_t)bh * 2048;

  // Q hi tile 128x128 -> LDS -> registers; then Q lo likewise (same LDS region)
  bf16x8 qf[2][4], qflo[2][4];
  stage_swz<128, 8>(Qhi + (bhT + q0) * 128, 128, smem, tid);
  __syncthreads();
  #pragma unroll
  for (int mt = 0; mt < 2; ++mt)
    #pragma unroll
    for (int kk = 0; kk < 4; ++kk)
      qf[mt][kk] = ld_frag(&smem[swz(w * 32 + mt * 16 + lr, kk * 32 + lq * 8, 128, 15)]);
  __syncthreads();
  stage_swz<128, 8>(Qlo + (bhT + q0) * 128, 128, smem, tid);
  __syncthreads();
  #pragma unroll
  for (int mt = 0; mt < 2; ++mt)
    #pragma unroll
    for (int kk = 0; kk < 4; ++kk)
      qflo[mt][kk] = ld_frag(&smem[swz(w * 32 + mt * 16 + lr, kk * 32 + lq * 8, 128, 15)]);
  __syncthreads();

  floatx4 oacc[2][8] = {};
  floatx4 den[2] = {};
  const ushort8_t onesu = {0x3F80, 0x3F80, 0x3F80, 0x3F80, 0x3F80, 0x3F80, 0x3F80, 0x3F80};
  const bf16x8 ones = __builtin_bit_cast(bf16x8, onesu);
  const float scale = 0.08838834764831845f;   // 1/sqrt(128)

  const int kend = q0 + 128;
  for (int k0 = 0; k0 < kend; k0 += 64) {
    stage_swz<128, 4>(Khi + (bhT + k0) * 128, 128, Ks, tid);
    stage_swz<128, 4>(Klo + (bhT + k0) * 128, 128, Kslo, tid);
    stage_swz<64, 4>(Vt + (size_t)bh * 128 * 2048 + k0, 2048, Vts, tid);
    __syncthreads();

    // S = Q K^T with hi/lo correction (per wave: 32 q-rows x 64 kp)
    floatx4 s[2][4] = {};
    #pragma unroll
    for (int kk = 0; kk < 4; ++kk) {
      bf16x8 kf[4], kflo[4];
      #pragma unroll
      for (int nt = 0; nt < 4; ++nt) {
        kf[nt]   = ld_frag(&Ks[swz(nt * 16 + lr, kk * 32 + lq * 8, 128, 15)]);
        kflo[nt] = ld_frag(&Kslo[swz(nt * 16 + lr, kk * 32 + lq * 8, 128, 15)]);
      }
      #pragma unroll
      for (int mt = 0; mt < 2; ++mt)
        #pragma unroll
        for (int nt = 0; nt < 4; ++nt) {
          s[mt][nt] = __builtin_amdgcn_mfma_f32_16x16x32_bf16(qf[mt][kk],   kf[nt],   s[mt][nt], 0, 0, 0);
          s[mt][nt] = __builtin_amdgcn_mfma_f32_16x16x32_bf16(qflo[mt][kk], kf[nt],   s[mt][nt], 0, 0, 0);
          s[mt][nt] = __builtin_amdgcn_mfma_f32_16x16x32_bf16(qf[mt][kk],   kflo[nt], s[mt][nt], 0, 0, 0);
        }
    }

    // mask + relu -> Ps (bf16)
    #pragma unroll
    for (int mt = 0; mt < 2; ++mt) {
      const int rb = w * 32 + mt * 16 + lq * 4;
      #pragma unroll
      for (int nt = 0; nt < 4; ++nt) {
        const int col = nt * 16 + lr;
        const int kg = k0 + col;
        #pragma unroll
        for (int r = 0; r < 4; ++r) {
          float v = s[mt][nt][r] * scale + 0.1f;   // relu(score - (-0.1))
          v = (kg <= q0 + rb + r) ? fmaxf(v, 0.0f) : 0.0f;
          Ps[swz(rb + r, col, 64, 7)] = f2bf(v);
        }
      }
    }
    __syncthreads();

    // O += P @ Vt^T ; den += P @ 1
    #pragma unroll
    for (int kk = 0; kk < 2; ++kk) {
      bf16x8 pf[2];
      #pragma unroll
      for (int mt = 0; mt < 2; ++mt)
        pf[mt] = ld_frag(&Ps[swz(w * 32 + mt * 16 + lr, kk * 32 + lq * 8, 64, 7)]);
      #pragma unroll
      for (int mt = 0; mt < 2; ++mt)
        den[mt] = __builtin_amdgcn_mfma_f32_16x16x32_bf16(pf[mt], ones, den[mt], 0, 0, 0);
      #pragma unroll
      for (int dt = 0; dt < 8; ++dt) {
        bf16x8 vf = ld_frag(&Vts[swz(dt * 16 + lr, kk * 32 + lq * 8, 64, 7)]);
        #pragma unroll
        for (int mt = 0; mt < 2; ++mt)
          oacc[mt][dt] = __builtin_amdgcn_mfma_f32_16x16x32_bf16(pf[mt], vf, oacc[mt][dt], 0, 0, 0);
      }
    }
    __syncthreads();
  }

  // epilogue: Ob is [B*T, 2048] bf16 (row m = b*2048 + t, col = h*128 + d)
  const int b = bh >> 4, h = bh & 15;
  #pragma unroll
  for (int mt = 0; mt < 2; ++mt) {
    #pragma unroll
    for (int r = 0; r < 4; ++r) {
      const int qrow = w * 32 + mt * 16 + lq * 4 + r;
      const float inv = 1.0f / (den[mt][r] + 1e-6f);
      u16* dst = Ob + ((size_t)(b * 2048 + q0 + qrow)) * 2048 + h * 128;
      #pragma unroll
      for (int dt = 0; dt < 8; ++dt)
        dst[dt * 16 + lr] = f2bf(oacc[mt][dt][r] * inv);
    }
  }
}

// ---------------------------------------------------------------- launch
extern "C" void kernel_launch(void* const* d_in, const int* in_sizes, int n_in,
                              void* d_out, int out_size, void* d_ws, size_t ws_size,
                              hipStream_t stream) {
  const float* x  = (const float*)d_in[0];
  const float* Wq = (const float*)d_in[1];
  const float* Wk = (const float*)d_in[2];
  const float* Wv = (const float*)d_in[3];
  const float* Wo = (const float*)d_in[4];
  float* out = (float*)d_out;

  const size_t MB = 1024 * 1024;
  char* ws = (char*)d_ws;
  // workspace (128 MB). Vh lives in d_out (dead before final GEMM writes it);
  // Ob aliases xb (xb dead after V GEMM).
  u16* xb  = (u16*)(ws);               // 16 MB  [4096, 2048] bf16 (later: Ob)
  u16* Wqb = (u16*)(ws + 16 * MB);     //  8 MB
  u16* Wkb = (u16*)(ws + 24 * MB);
  u16* Wvb = (u16*)(ws + 32 * MB);
  u16* Wob = (u16*)(ws + 40 * MB);
  u16* Qhi = (u16*)(ws + 48 * MB);     // 16 MB  [BH, T, 128]
  u16* Qlo = (u16*)(ws + 64 * MB);     // 16 MB
  u16* Khi = (u16*)(ws + 80 * MB);     // 16 MB
  u16* Klo = (u16*)(ws + 96 * MB);     // 16 MB
  u16* Vt  = (u16*)(ws + 112 * MB);    // 16 MB  [BH, 128, T]
  u16* Vh  = (u16*)d_out;              // 16 MB scratch inside d_out (33.5 MB)
  u16* Ob  = xb;

  const int nx = 2 * 2048 * 2048;
  const int nw = 2048 * 2048;

  f32_to_bf16_kernel<<<nx / 1024, 256, 0, stream>>>(x,  xb,  nx);
  f32_to_bf16_kernel<<<nw / 1024, 256, 0, stream>>>(Wq, Wqb, nw);
  f32_to_bf16_kernel<<<nw / 1024, 256, 0, stream>>>(Wk, Wkb, nw);
  f32_to_bf16_kernel<<<nw / 1024, 256, 0, stream>>>(Wv, Wvb, nw);
  f32_to_bf16_kernel<<<nw / 1024, 256, 0, stream>>>(Wo, Wob, nw);

  dim3 gg(2048 / 128, 4096 / 128);     // (16, 32)
  gemm_bt<2><<<gg, 256, 0, stream>>>(xb, Wqb, (void*)Qhi, (void*)Qlo, 4096, 2048, 2048);
  gemm_bt<2><<<gg, 256, 0, stream>>>(xb, Wkb, (void*)Khi, (void*)Klo, 4096, 2048, 2048);
  gemm_bt<0><<<gg, 256, 0, stream>>>(xb, Wvb, (void*)Vh, nullptr, 4096, 2048, 2048);

  transpose_v<<<dim3(32, 32, 2), 256, 0, stream>>>(Vh, Vt);

  attn_kernel<<<dim3(32, 16), 256, 0, stream>>>(Qhi, Qlo, Khi, Klo, Vt, Ob);

  gemm_bt<1><<<gg, 256, 0, stream>>>(Ob, Wob, (void*)out, nullptr, 4096, 2048, 2048);
}

// Round 3
// 417.944 us; speedup vs baseline: 1.1515x; 1.1515x over previous
//
#include <hip/hip_runtime.h>
#include <stdint.h>

// GhostAttention on MI355X (gfx950). B=2, T=2048, C=2048, H=16, hd=128.
// All-fp16 pipeline (fp16 eps 2^-11): convert -> fused QKV GEMM (Q stored
// hi/lo fp16 for fp32-accurate scores; K,V single fp16) -> V transpose ->
// causal relu-attention, linear normalizer -> out GEMM (fp16 in, fp32 out).

typedef unsigned short u16;
typedef _Float16 f16x8 __attribute__((ext_vector_type(8)));
typedef float floatx4 __attribute__((ext_vector_type(4)));
typedef unsigned short ushort8_t __attribute__((ext_vector_type(8)));

__device__ __forceinline__ u16 f2h(float f) {
  _Float16 h = (_Float16)f;                  // v_cvt_f16_f32, RNE
  return __builtin_bit_cast(u16, h);
}
__device__ __forceinline__ float h2f(u16 u) {
  return (float)__builtin_bit_cast(_Float16, u);
}
__device__ __forceinline__ f16x8 ld_frag(const u16* p) {
  return __builtin_bit_cast(f16x8, *(const ushort8_t*)p);
}

// XOR-swizzled LDS offset: row length R elems (R%8==0), cprMask = R/8-1.
__device__ __forceinline__ int swz(int row, int col, int R, int cprMask) {
  int chunk = ((col >> 3) ^ row) & cprMask;
  return row * R + chunk * 8 + (col & 7);
}

__device__ __forceinline__ void async_copy16(const void* g, void* l) {
  __builtin_amdgcn_global_load_lds(
      (const __attribute__((address_space(1))) void*)g,
      (__attribute__((address_space(3))) void*)l, 16, 0, 0);
}

// Stage (NINST*2048/R) rows x R fp16 from global (row stride grs) into swizzled LDS.
template<int R, int NINST>
__device__ __forceinline__ void stage_swz(const u16* g, size_t grs, u16* lds, int tid) {
  constexpr int CPR = R / 8;
  #pragma unroll
  for (int i = 0; i < NINST; ++i) {
    int f = tid + i * 256;
    int row = f / CPR;
    int sc = f & (CPR - 1);
    int c = sc ^ (row & (CPR - 1));
    async_copy16(g + (size_t)row * grs + c * 8, (char*)lds + f * 16);
  }
}

// ---------------------------------------------------------------- converts
__global__ void f32_to_f16_kernel(const float* __restrict__ in, u16* __restrict__ out, int n) {
  int i = (blockIdx.x * blockDim.x + threadIdx.x) * 4;
  if (i < n) {
    float4 v = *(const float4*)(in + i);
    ushort4 o;
    o.x = f2h(v.x); o.y = f2h(v.y); o.z = f2h(v.z); o.w = f2h(v.w);
    *(ushort4*)(out + i) = o;
  }
}

__global__ void w4_to_f16_kernel(const float* w0, const float* w1, const float* w2, const float* w3,
                                 u16* o0, u16* o1, u16* o2, u16* o3, int n) {
  const float* in = (blockIdx.y == 0) ? w0 : (blockIdx.y == 1) ? w1 : (blockIdx.y == 2) ? w2 : w3;
  u16* out = (blockIdx.y == 0) ? o0 : (blockIdx.y == 1) ? o1 : (blockIdx.y == 2) ? o2 : o3;
  int i = (blockIdx.x * blockDim.x + threadIdx.x) * 4;
  if (i < n) {
    float4 v = *(const float4*)(in + i);
    ushort4 o;
    o.x = f2h(v.x); o.y = f2h(v.y); o.z = f2h(v.z); o.w = f2h(v.w);
    *(ushort4*)(out + i) = o;
  }
}

// ---------------------------------------------------------------- GEMM (B^T)
// C = A[M,K] @ B[N,K]^T, fp16 in, fp32 accum. 128x128 tile, BK=32.
// MODE 1: fp32 row-major C0[M,N]   (final projection)
// MODE 3: fused QKV: N=6144; n<2048 -> Q hi/lo (C0,C1); <4096 -> K (C2); else V (C3).
//         Q/K/V stored head-major fp16 [B,H,T,128].
template<int MODE>
__global__ __launch_bounds__(256, 2) void gemm_bt(
    const u16* __restrict__ A,
    const u16* __restrict__ B0, const u16* __restrict__ B1, const u16* __restrict__ B2,
    void* __restrict__ C0, void* __restrict__ C1, void* __restrict__ C2, void* __restrict__ C3,
    const int M, const int N, const int K)
{
  __shared__ __align__(16) u16 As[128 * 32];
  __shared__ __align__(16) u16 Bs[128 * 32];
  const int tid = threadIdx.x;
  const int w = tid >> 6, lane = tid & 63, lr = lane & 15, lq = lane >> 4;
  const int bn0 = blockIdx.x * 128, bm0 = blockIdx.y * 128;
  const int wm = (w >> 1) * 64, wn = (w & 1) * 64;
  floatx4 acc[4][4] = {};
  const u16* Ab = A + (size_t)bm0 * K;
  const int sel = bn0 >> 11;                  // which weight (MODE 3)
  const u16* Bb;
  if (MODE == 3) {
    const u16* Bsel = (sel == 0) ? B0 : (sel == 1) ? B1 : B2;
    Bb = Bsel + (size_t)(bn0 & 2047) * K;
  } else {
    Bb = B0 + (size_t)bn0 * K;
  }

  for (int k0 = 0; k0 < K; k0 += 32) {
    __syncthreads();
    stage_swz<32, 2>(Ab + k0, K, As, tid);
    stage_swz<32, 2>(Bb + k0, K, Bs, tid);
    __syncthreads();
    f16x8 af[4], bfr[4];
    #pragma unroll
    for (int t = 0; t < 4; ++t) {
      af[t]  = ld_frag(&As[swz(wm + t * 16 + lr, lq * 8, 32, 3)]);
      bfr[t] = ld_frag(&Bs[swz(wn + t * 16 + lr, lq * 8, 32, 3)]);
    }
    #pragma unroll
    for (int mt = 0; mt < 4; ++mt)
      #pragma unroll
      for (int nt = 0; nt < 4; ++nt)
        acc[mt][nt] = __builtin_amdgcn_mfma_f32_16x16x32_f16(af[mt], bfr[nt], acc[mt][nt], 0, 0, 0);
  }

  // epilogue: C/D layout col=lane&15, row=(lane>>4)*4+reg
  #pragma unroll
  for (int mt = 0; mt < 4; ++mt) {
    #pragma unroll
    for (int nt = 0; nt < 4; ++nt) {
      #pragma unroll
      for (int r = 0; r < 4; ++r) {
        const int m = bm0 + wm + mt * 16 + lq * 4 + r;
        const int n = bn0 + wn + nt * 16 + lr;
        const float v = acc[mt][nt][r];
        if (MODE == 1) {
          ((float*)C0)[(size_t)m * N + n] = v;
        } else {
          const int nn = n & 2047;
          const int bb = m >> 11, t = m & 2047, h = nn >> 7, d = nn & 127;
          const size_t idx = (((size_t)(bb * 16 + h) * 2048) + t) * 128 + d;
          if (sel == 0) {
            const u16 hi = f2h(v);
            ((u16*)C0)[idx] = hi;
            ((u16*)C1)[idx] = f2h(v - h2f(hi));
          } else if (sel == 1) {
            ((u16*)C2)[idx] = f2h(v);
          } else {
            ((u16*)C3)[idx] = f2h(v);
          }
        }
      }
    }
  }
}

// ---------------------------------------------------------------- V transpose
// Vh [BH, T=2048, 128] -> Vt [BH, 128, T=2048]
__global__ void transpose_v(const u16* __restrict__ Vh, u16* __restrict__ Vt) {
  __shared__ u16 tile[64][65];
  const int bh = blockIdx.x, t0 = blockIdx.y * 64, d0 = blockIdx.z * 64;
  const int tid = threadIdx.x;
  const u16* src = Vh + ((size_t)bh * 2048 + t0) * 128 + d0;
  #pragma unroll
  for (int i = 0; i < 16; ++i) {
    int e = tid + i * 256;
    int r = e >> 6, c = e & 63;
    tile[r][c] = src[(size_t)r * 128 + c];
  }
  __syncthreads();
  u16* dst = Vt + ((size_t)bh * 128 + d0) * 2048 + t0;
  #pragma unroll
  for (int i = 0; i < 16; ++i) {
    int e = tid + i * 256;
    int r = e >> 6, c = e & 63;
    dst[(size_t)r * 2048 + c] = tile[c][r];
  }
}

// ---------------------------------------------------------------- attention
// Block: one (bh, 128-row q-tile). k-tiles of 64. out = (P@V)/(P@1 + eps),
// P = relu(S*scale + 0.1), causal. S = (qhi + qlo) @ k  (fp16 hi/lo Q, single-K;
// K-rounding error ~5e-4, well under tolerance). Ps aliases Ks (dead after QK).
__global__ __launch_bounds__(256, 2) void attn_kernel(
    const u16* __restrict__ Qhi, const u16* __restrict__ Qlo,
    const u16* __restrict__ Kh, const u16* __restrict__ Vt, u16* __restrict__ Ob)
{
  __shared__ __align__(16) u16 smem[16384];   // 32 KB
  u16* Ks  = smem;            // [64][128] swz cpr16; aliased by Ps [128][64] cpr8
  u16* Ps  = smem;
  u16* Vts = smem + 8192;     // [128][64] swz cpr8
  const int tid = threadIdx.x;
  const int w = tid >> 6, lane = tid & 63, lr = lane & 15, lq = lane >> 4;
  const int bh = blockIdx.x;
  const int y = blockIdx.y;
  // complementary interleave: blocks i and i+256 have qt summing to 15 ->
  // round-robin CU pairing gets uniform 34 k-iters per CU
  const int qt = (y < 8) ? (15 - y) : (y - 8);
  const int q0 = qt * 128;
  const size_t bhT = (size_t)bh * 2048;

  // Q hi then Q lo: stage 128x128 through full 32KB smem -> registers
  f16x8 qf[2][4], qflo[2][4];
  stage_swz<128, 8>(Qhi + (bhT + q0) * 128, 128, smem, tid);
  __syncthreads();
  #pragma unroll
  for (int mt = 0; mt < 2; ++mt)
    #pragma unroll
    for (int kk = 0; kk < 4; ++kk)
      qf[mt][kk] = ld_frag(&smem[swz(w * 32 + mt * 16 + lr, kk * 32 + lq * 8, 128, 15)]);
  __syncthreads();
  stage_swz<128, 8>(Qlo + (bhT + q0) * 128, 128, smem, tid);
  __syncthreads();
  #pragma unroll
  for (int mt = 0; mt < 2; ++mt)
    #pragma unroll
    for (int kk = 0; kk < 4; ++kk)
      qflo[mt][kk] = ld_frag(&smem[swz(w * 32 + mt * 16 + lr, kk * 32 + lq * 8, 128, 15)]);
  __syncthreads();

  floatx4 oacc[2][8] = {};
  floatx4 den[2] = {};
  const ushort8_t onesu = {0x3C00, 0x3C00, 0x3C00, 0x3C00, 0x3C00, 0x3C00, 0x3C00, 0x3C00};
  const f16x8 ones = __builtin_bit_cast(f16x8, onesu);
  const float scale = 0.08838834764831845f;   // 1/sqrt(128)

  const int kend = q0 + 128;
  for (int k0 = 0; k0 < kend; k0 += 64) {
    stage_swz<128, 4>(Kh + (bhT + k0) * 128, 128, Ks, tid);
    stage_swz<64, 4>(Vt + (size_t)bh * 128 * 2048 + k0, 2048, Vts, tid);
    __syncthreads();                          // staging visible

    // S = (qhi + qlo) K^T : 32 q-rows x 64 keys per wave
    floatx4 s[2][4] = {};
    #pragma unroll
    for (int kk = 0; kk < 4; ++kk) {
      f16x8 kf[4];
      #pragma unroll
      for (int nt = 0; nt < 4; ++nt)
        kf[nt] = ld_frag(&Ks[swz(nt * 16 + lr, kk * 32 + lq * 8, 128, 15)]);
      #pragma unroll
      for (int mt = 0; mt < 2; ++mt)
        #pragma unroll
        for (int nt = 0; nt < 4; ++nt) {
          s[mt][nt] = __builtin_amdgcn_mfma_f32_16x16x32_f16(qf[mt][kk],   kf[nt], s[mt][nt], 0, 0, 0);
          s[mt][nt] = __builtin_amdgcn_mfma_f32_16x16x32_f16(qflo[mt][kk], kf[nt], s[mt][nt], 0, 0, 0);
        }
    }
    __syncthreads();                          // all waves done with Ks

    // P = relu(S*scale + 0.1) (+causal mask on the 2 diagonal-band tiles)
    if (k0 < q0) {                            // interior: no mask needed
      #pragma unroll
      for (int mt = 0; mt < 2; ++mt) {
        const int rb = w * 32 + mt * 16 + lq * 4;
        #pragma unroll
        for (int nt = 0; nt < 4; ++nt) {
          const int col = nt * 16 + lr;
          #pragma unroll
          for (int r = 0; r < 4; ++r)
            Ps[swz(rb + r, col, 64, 7)] = f2h(fmaxf(s[mt][nt][r] * scale + 0.1f, 0.0f));
        }
      }
    } else {
      #pragma unroll
      for (int mt = 0; mt < 2; ++mt) {
        const int rb = w * 32 + mt * 16 + lq * 4;
        #pragma unroll
        for (int nt = 0; nt < 4; ++nt) {
          const int col = nt * 16 + lr;
          const int kg = k0 + col;
          #pragma unroll
          for (int r = 0; r < 4; ++r) {
            float v = fmaxf(s[mt][nt][r] * scale + 0.1f, 0.0f);
            v = (kg <= q0 + rb + r) ? v : 0.0f;
            Ps[swz(rb + r, col, 64, 7)] = f2h(v);
          }
        }
      }
    }
    __syncthreads();                          // Ps visible

    // O += P @ Vt^T ; den += P @ 1
    #pragma unroll
    for (int kk = 0; kk < 2; ++kk) {
      f16x8 pf[2];
      #pragma unroll
      for (int mt = 0; mt < 2; ++mt)
        pf[mt] = ld_frag(&Ps[swz(w * 32 + mt * 16 + lr, kk * 32 + lq * 8, 64, 7)]);
      #pragma unroll
      for (int mt = 0; mt < 2; ++mt)
        den[mt] = __builtin_amdgcn_mfma_f32_16x16x32_f16(pf[mt], ones, den[mt], 0, 0, 0);
      #pragma unroll
      for (int dt = 0; dt < 8; ++dt) {
        f16x8 vf = ld_frag(&Vts[swz(dt * 16 + lr, kk * 32 + lq * 8, 64, 7)]);
        #pragma unroll
        for (int mt = 0; mt < 2; ++mt)
          oacc[mt][dt] = __builtin_amdgcn_mfma_f32_16x16x32_f16(pf[mt], vf, oacc[mt][dt], 0, 0, 0);
      }
    }
    __syncthreads();                          // done with Ps/Vts before next stage
  }

  // epilogue: Ob [B*T, 2048] fp16 (row = b*2048 + t, col = h*128 + d)
  const int b = bh >> 4, h = bh & 15;
  #pragma unroll
  for (int mt = 0; mt < 2; ++mt) {
    #pragma unroll
    for (int r = 0; r < 4; ++r) {
      const int qrow = w * 32 + mt * 16 + lq * 4 + r;
      const float inv = 1.0f / (den[mt][r] + 1e-6f);
      u16* dst = Ob + ((size_t)(b * 2048 + q0 + qrow)) * 2048 + h * 128;
      #pragma unroll
      for (int dt = 0; dt < 8; ++dt)
        dst[dt * 16 + lr] = f2h(oacc[mt][dt][r] * inv);
    }
  }
}

// ---------------------------------------------------------------- launch
extern "C" void kernel_launch(void* const* d_in, const int* in_sizes, int n_in,
                              void* d_out, int out_size, void* d_ws, size_t ws_size,
                              hipStream_t stream) {
  const float* x  = (const float*)d_in[0];
  const float* Wq = (const float*)d_in[1];
  const float* Wk = (const float*)d_in[2];
  const float* Wv = (const float*)d_in[3];
  const float* Wo = (const float*)d_in[4];
  float* out = (float*)d_out;

  const size_t MB = 1024 * 1024;
  char* ws = (char*)d_ws;
  // workspace (112 MB). Vh scratch lives in d_out (dead before final GEMM);
  // Ob aliases xb (dead after QKV GEMM).
  u16* xb  = (u16*)(ws);               // 16 MB [4096,2048] fp16 (later Ob)
  u16* Wqb = (u16*)(ws + 16 * MB);     //  8 MB each
  u16* Wkb = (u16*)(ws + 24 * MB);
  u16* Wvb = (u16*)(ws + 32 * MB);
  u16* Wob = (u16*)(ws + 40 * MB);
  u16* Qhi = (u16*)(ws + 48 * MB);     // 16 MB [BH,T,128]
  u16* Qlo = (u16*)(ws + 64 * MB);     // 16 MB
  u16* Khi = (u16*)(ws + 80 * MB);     // 16 MB
  u16* Vt  = (u16*)(ws + 96 * MB);     // 16 MB [BH,128,T]
  u16* Vh  = (u16*)d_out;              // 16 MB scratch in d_out (33.5 MB)
  u16* Ob  = xb;

  const int nx = 2 * 2048 * 2048;
  const int nw = 2048 * 2048;

  f32_to_f16_kernel<<<nx / 1024, 256, 0, stream>>>(x, xb, nx);
  w4_to_f16_kernel<<<dim3(nw / 1024, 4), 256, 0, stream>>>(Wq, Wk, Wv, Wo, Wqb, Wkb, Wvb, Wob, nw);

  // fused QKV: N = 6144
  gemm_bt<3><<<dim3(6144 / 128, 4096 / 128), 256, 0, stream>>>(
      xb, Wqb, Wkb, Wvb, (void*)Qhi, (void*)Qlo, (void*)Khi, (void*)Vh, 4096, 6144, 2048);

  transpose_v<<<dim3(32, 32, 2), 256, 0, stream>>>(Vh, Vt);

  attn_kernel<<<dim3(32, 16), 256, 0, stream>>>(Qhi, Qlo, Khi, Vt, Ob);

  gemm_bt<1><<<dim3(2048 / 128, 4096 / 128), 256, 0, stream>>>(
      Ob, Wob, nullptr, nullptr, (void*)out, nullptr, nullptr, nullptr, 4096, 2048, 2048);
}

// Round 4
// 361.224 us; speedup vs baseline: 1.3323x; 1.1570x over previous
//
#include <hip/hip_runtime.h>
#include <stdint.h>

// GhostAttention on MI355X (gfx950). B=2, T=2048, C=2048, H=16, hd=128.
// All-fp16 pipeline: convert -> fused QKV GEMM (BK=64, conflict-free LDS) ->
// V transpose -> causal relu-attention (linear normalizer, single fp16 Q/K) ->
// out GEMM (fp16 in, fp32 out).

typedef unsigned short u16;
typedef _Float16 f16x8 __attribute__((ext_vector_type(8)));
typedef float floatx4 __attribute__((ext_vector_type(4)));
typedef unsigned short ushort8_t __attribute__((ext_vector_type(8)));

__device__ __forceinline__ u16 f2h(float f) {
  _Float16 h = (_Float16)f;                  // v_cvt_f16_f32, RNE
  return __builtin_bit_cast(u16, h);
}
__device__ __forceinline__ f16x8 ld_frag(const u16* p) {
  return __builtin_bit_cast(f16x8, *(const ushort8_t*)p);
}

// XOR-swizzled LDS offset: row length R elems (R%8==0), cprMask = R/8-1.
// R=64 rows are 128B = all 32 banks; 16-row ds_read_b128 access -> uniform
// 2-way bank aliasing (free). R=32 (4-way collisions, 1.26e7 conflicts) removed.
__device__ __forceinline__ int swz(int row, int col, int R, int cprMask) {
  int chunk = ((col >> 3) ^ row) & cprMask;
  return row * R + chunk * 8 + (col & 7);
}

__device__ __forceinline__ void async_copy16(const void* g, void* l) {
  __builtin_amdgcn_global_load_lds(
      (const __attribute__((address_space(1))) void*)g,
      (__attribute__((address_space(3))) void*)l, 16, 0, 0);
}

// Stage (NINST*2048/R) rows x R fp16 from global (row stride grs) into swizzled LDS.
template<int R, int NINST>
__device__ __forceinline__ void stage_swz(const u16* g, size_t grs, u16* lds, int tid) {
  constexpr int CPR = R / 8;
  #pragma unroll
  for (int i = 0; i < NINST; ++i) {
    int f = tid + i * 256;
    int row = f / CPR;
    int sc = f & (CPR - 1);
    int c = sc ^ (row & (CPR - 1));
    async_copy16(g + (size_t)row * grs + c * 8, (char*)lds + f * 16);
  }
}

// ---------------------------------------------------------------- converts
__global__ void f32_to_f16_kernel(const float* __restrict__ in, u16* __restrict__ out, int n) {
  int i = (blockIdx.x * blockDim.x + threadIdx.x) * 4;
  if (i < n) {
    float4 v = *(const float4*)(in + i);
    ushort4 o;
    o.x = f2h(v.x); o.y = f2h(v.y); o.z = f2h(v.z); o.w = f2h(v.w);
    *(ushort4*)(out + i) = o;
  }
}

__global__ void w4_to_f16_kernel(const float* w0, const float* w1, const float* w2, const float* w3,
                                 u16* o0, u16* o1, u16* o2, u16* o3, int n) {
  const float* in = (blockIdx.y == 0) ? w0 : (blockIdx.y == 1) ? w1 : (blockIdx.y == 2) ? w2 : w3;
  u16* out = (blockIdx.y == 0) ? o0 : (blockIdx.y == 1) ? o1 : (blockIdx.y == 2) ? o2 : o3;
  int i = (blockIdx.x * blockDim.x + threadIdx.x) * 4;
  if (i < n) {
    float4 v = *(const float4*)(in + i);
    ushort4 o;
    o.x = f2h(v.x); o.y = f2h(v.y); o.z = f2h(v.z); o.w = f2h(v.w);
    *(ushort4*)(out + i) = o;
  }
}

// ---------------------------------------------------------------- GEMM (B^T)
// C = A[M,K] @ B[N,K]^T, fp16 in, fp32 accum. 128x128 tile, BK=64.
// MODE 1: fp32 row-major C0[M,N]   (final projection)
// MODE 3: fused QKV: N=6144; sel = n/2048 -> Q (C0) / K (C1) / V (C2),
//         each stored head-major fp16 [B,H,T,128].
template<int MODE>
__global__ __launch_bounds__(256, 3) void gemm_bt(
    const u16* __restrict__ A,
    const u16* __restrict__ B0, const u16* __restrict__ B1, const u16* __restrict__ B2,
    void* __restrict__ C0, void* __restrict__ C1, void* __restrict__ C2,
    const int M, const int N, const int K)
{
  __shared__ __align__(16) u16 As[128 * 64];   // 16 KB
  __shared__ __align__(16) u16 Bs[128 * 64];   // 16 KB
  const int tid = threadIdx.x;
  const int w = tid >> 6, lane = tid & 63, lr = lane & 15, lq = lane >> 4;
  const int bn0 = blockIdx.x * 128, bm0 = blockIdx.y * 128;
  const int wm = (w >> 1) * 64, wn = (w & 1) * 64;
  floatx4 acc[4][4] = {};
  const u16* Ab = A + (size_t)bm0 * K;
  const int sel = bn0 >> 11;                  // which output (MODE 3)
  const u16* Bb;
  if (MODE == 3) {
    const u16* Bsel = (sel == 0) ? B0 : (sel == 1) ? B1 : B2;
    Bb = Bsel + (size_t)(bn0 & 2047) * K;
  } else {
    Bb = B0 + (size_t)bn0 * K;
  }

  for (int k0 = 0; k0 < K; k0 += 64) {
    __syncthreads();
    stage_swz<64, 4>(Ab + k0, K, As, tid);
    stage_swz<64, 4>(Bb + k0, K, Bs, tid);
    __syncthreads();
    #pragma unroll
    for (int kk = 0; kk < 2; ++kk) {
      f16x8 af[4], bfr[4];
      #pragma unroll
      for (int t = 0; t < 4; ++t) {
        af[t]  = ld_frag(&As[swz(wm + t * 16 + lr, kk * 32 + lq * 8, 64, 7)]);
        bfr[t] = ld_frag(&Bs[swz(wn + t * 16 + lr, kk * 32 + lq * 8, 64, 7)]);
      }
      #pragma unroll
      for (int mt = 0; mt < 4; ++mt)
        #pragma unroll
        for (int nt = 0; nt < 4; ++nt)
          acc[mt][nt] = __builtin_amdgcn_mfma_f32_16x16x32_f16(af[mt], bfr[nt], acc[mt][nt], 0, 0, 0);
    }
  }

  // epilogue: C/D layout col=lane&15, row=(lane>>4)*4+reg
  #pragma unroll
  for (int mt = 0; mt < 4; ++mt) {
    #pragma unroll
    for (int nt = 0; nt < 4; ++nt) {
      #pragma unroll
      for (int r = 0; r < 4; ++r) {
        const int m = bm0 + wm + mt * 16 + lq * 4 + r;
        const int n = bn0 + wn + nt * 16 + lr;
        const float v = acc[mt][nt][r];
        if (MODE == 1) {
          ((float*)C0)[(size_t)m * N + n] = v;
        } else {
          const int nn = n & 2047;
          const int bb = m >> 11, t = m & 2047, h = nn >> 7, d = nn & 127;
          const size_t idx = (((size_t)(bb * 16 + h) * 2048) + t) * 128 + d;
          u16* Cs = (sel == 0) ? (u16*)C0 : (sel == 1) ? (u16*)C1 : (u16*)C2;
          Cs[idx] = f2h(v);
        }
      }
    }
  }
}

// ---------------------------------------------------------------- V transpose
// Vh [BH, T=2048, 128] -> Vt [BH, 128, T=2048]
__global__ void transpose_v(const u16* __restrict__ Vh, u16* __restrict__ Vt) {
  __shared__ u16 tile[64][65];
  const int bh = blockIdx.x, t0 = blockIdx.y * 64, d0 = blockIdx.z * 64;
  const int tid = threadIdx.x;
  const u16* src = Vh + ((size_t)bh * 2048 + t0) * 128 + d0;
  #pragma unroll
  for (int i = 0; i < 16; ++i) {
    int e = tid + i * 256;
    int r = e >> 6, c = e & 63;
    tile[r][c] = src[(size_t)r * 128 + c];
  }
  __syncthreads();
  u16* dst = Vt + ((size_t)bh * 128 + d0) * 2048 + t0;
  #pragma unroll
  for (int i = 0; i < 16; ++i) {
    int e = tid + i * 256;
    int r = e >> 6, c = e & 63;
    dst[(size_t)r * 2048 + c] = tile[c][r];
  }
}

// ---------------------------------------------------------------- attention
// Block: one (bh, 128-row q-tile). k-tiles of 64. out = (P@V)/(P@1 + eps),
// P = relu(S*scale + 0.1), causal. Single fp16 Q and K (fp16 rounding error
// ~0.02 at output, threshold 0.066). Ps aliases Ks (dead after QK).
__global__ __launch_bounds__(256, 2) void attn_kernel(
    const u16* __restrict__ Qh, const u16* __restrict__ Kh,
    const u16* __restrict__ Vt, u16* __restrict__ Ob)
{
  __shared__ __align__(16) u16 smem[16384];   // 32 KB
  u16* Ks  = smem;            // [64][128] swz cpr16; aliased by Ps [128][64] cpr8
  u16* Ps  = smem;
  u16* Vts = smem + 8192;     // [128][64] swz cpr8
  const int tid = threadIdx.x;
  const int w = tid >> 6, lane = tid & 63, lr = lane & 15, lq = lane >> 4;
  const int bh = blockIdx.x;
  const int y = blockIdx.y;
  // complementary interleave: blocks y and y+8 have qt summing to 15 ->
  // round-robin CU assignment gets uniform k-iter load
  const int qt = (y < 8) ? (15 - y) : (y - 8);
  const int q0 = qt * 128;
  const size_t bhT = (size_t)bh * 2048;

  // Q tile 128x128 through full 32KB smem -> registers
  f16x8 qf[2][4];
  stage_swz<128, 8>(Qh + (bhT + q0) * 128, 128, smem, tid);
  __syncthreads();
  #pragma unroll
  for (int mt = 0; mt < 2; ++mt)
    #pragma unroll
    for (int kk = 0; kk < 4; ++kk)
      qf[mt][kk] = ld_frag(&smem[swz(w * 32 + mt * 16 + lr, kk * 32 + lq * 8, 128, 15)]);
  __syncthreads();

  floatx4 oacc[2][8] = {};
  floatx4 den[2] = {};
  const ushort8_t onesu = {0x3C00, 0x3C00, 0x3C00, 0x3C00, 0x3C00, 0x3C00, 0x3C00, 0x3C00};
  const f16x8 ones = __builtin_bit_cast(f16x8, onesu);
  const float scale = 0.08838834764831845f;   // 1/sqrt(128)

  const int kend = q0 + 128;
  for (int k0 = 0; k0 < kend; k0 += 64) {
    stage_swz<128, 4>(Kh + (bhT + k0) * 128, 128, Ks, tid);
    stage_swz<64, 4>(Vt + (size_t)bh * 128 * 2048 + k0, 2048, Vts, tid);
    __syncthreads();                          // staging visible

    // S = Q K^T : 32 q-rows x 64 keys per wave
    floatx4 s[2][4] = {};
    #pragma unroll
    for (int kk = 0; kk < 4; ++kk) {
      f16x8 kf[4];
      #pragma unroll
      for (int nt = 0; nt < 4; ++nt)
        kf[nt] = ld_frag(&Ks[swz(nt * 16 + lr, kk * 32 + lq * 8, 128, 15)]);
      #pragma unroll
      for (int mt = 0; mt < 2; ++mt)
        #pragma unroll
        for (int nt = 0; nt < 4; ++nt)
          s[mt][nt] = __builtin_amdgcn_mfma_f32_16x16x32_f16(qf[mt][kk], kf[nt], s[mt][nt], 0, 0, 0);
    }
    __syncthreads();                          // all waves done reading Ks

    // P = relu(S*scale + 0.1) (+causal mask only on diagonal-band tiles)
    if (k0 < q0) {                            // interior: no mask needed
      #pragma unroll
      for (int mt = 0; mt < 2; ++mt) {
        const int rb = w * 32 + mt * 16 + lq * 4;
        #pragma unroll
        for (int nt = 0; nt < 4; ++nt) {
          const int col = nt * 16 + lr;
          #pragma unroll
          for (int r = 0; r < 4; ++r)
            Ps[swz(rb + r, col, 64, 7)] = f2h(fmaxf(s[mt][nt][r] * scale + 0.1f, 0.0f));
        }
      }
    } else {
      #pragma unroll
      for (int mt = 0; mt < 2; ++mt) {
        const int rb = w * 32 + mt * 16 + lq * 4;
        #pragma unroll
        for (int nt = 0; nt < 4; ++nt) {
          const int col = nt * 16 + lr;
          const int kg = k0 + col;
          #pragma unroll
          for (int r = 0; r < 4; ++r) {
            float v = fmaxf(s[mt][nt][r] * scale + 0.1f, 0.0f);
            v = (kg <= q0 + rb + r) ? v : 0.0f;
            Ps[swz(rb + r, col, 64, 7)] = f2h(v);
          }
        }
      }
    }
    __syncthreads();                          // Ps visible

    // O += P @ Vt^T ; den += P @ 1
    #pragma unroll
    for (int kk = 0; kk < 2; ++kk) {
      f16x8 pf[2];
      #pragma unroll
      for (int mt = 0; mt < 2; ++mt)
        pf[mt] = ld_frag(&Ps[swz(w * 32 + mt * 16 + lr, kk * 32 + lq * 8, 64, 7)]);
      #pragma unroll
      for (int mt = 0; mt < 2; ++mt)
        den[mt] = __builtin_amdgcn_mfma_f32_16x16x32_f16(pf[mt], ones, den[mt], 0, 0, 0);
      #pragma unroll
      for (int dt = 0; dt < 8; ++dt) {
        f16x8 vf = ld_frag(&Vts[swz(dt * 16 + lr, kk * 32 + lq * 8, 64, 7)]);
        #pragma unroll
        for (int mt = 0; mt < 2; ++mt)
          oacc[mt][dt] = __builtin_amdgcn_mfma_f32_16x16x32_f16(pf[mt], vf, oacc[mt][dt], 0, 0, 0);
      }
    }
    __syncthreads();                          // done with Ps/Vts before next stage
  }

  // epilogue: Ob [B*T, 2048] fp16 (row = b*2048 + t, col = h*128 + d)
  const int b = bh >> 4, h = bh & 15;
  #pragma unroll
  for (int mt = 0; mt < 2; ++mt) {
    #pragma unroll
    for (int r = 0; r < 4; ++r) {
      const int qrow = w * 32 + mt * 16 + lq * 4 + r;
      const float inv = 1.0f / (den[mt][r] + 1e-6f);
      u16* dst = Ob + ((size_t)(b * 2048 + q0 + qrow)) * 2048 + h * 128;
      #pragma unroll
      for (int dt = 0; dt < 8; ++dt)
        dst[dt * 16 + lr] = f2h(oacc[mt][dt][r] * inv);
    }
  }
}

// ---------------------------------------------------------------- launch
extern "C" void kernel_launch(void* const* d_in, const int* in_sizes, int n_in,
                              void* d_out, int out_size, void* d_ws, size_t ws_size,
                              hipStream_t stream) {
  const float* x  = (const float*)d_in[0];
  const float* Wq = (const float*)d_in[1];
  const float* Wk = (const float*)d_in[2];
  const float* Wv = (const float*)d_in[3];
  const float* Wo = (const float*)d_in[4];
  float* out = (float*)d_out;

  const size_t MB = 1024 * 1024;
  char* ws = (char*)d_ws;
  // workspace (96 MB). Vh scratch lives in d_out (dead before final GEMM);
  // Ob aliases xb (dead after QKV GEMM).
  u16* xb  = (u16*)(ws);               // 16 MB [4096,2048] fp16 (later Ob)
  u16* Wqb = (u16*)(ws + 16 * MB);     //  8 MB each
  u16* Wkb = (u16*)(ws + 24 * MB);
  u16* Wvb = (u16*)(ws + 32 * MB);
  u16* Wob = (u16*)(ws + 40 * MB);
  u16* Qh  = (u16*)(ws + 48 * MB);     // 16 MB [BH,T,128]
  u16* Kh  = (u16*)(ws + 64 * MB);     // 16 MB
  u16* Vt  = (u16*)(ws + 80 * MB);     // 16 MB [BH,128,T]
  u16* Vh  = (u16*)d_out;              // 16 MB scratch in d_out (33.5 MB)
  u16* Ob  = xb;

  const int nx = 2 * 2048 * 2048;
  const int nw = 2048 * 2048;

  f32_to_f16_kernel<<<nx / 1024, 256, 0, stream>>>(x, xb, nx);
  w4_to_f16_kernel<<<dim3(nw / 1024, 4), 256, 0, stream>>>(Wq, Wk, Wv, Wo, Wqb, Wkb, Wvb, Wob, nw);

  // fused QKV: N = 6144
  gemm_bt<3><<<dim3(6144 / 128, 4096 / 128), 256, 0, stream>>>(
      xb, Wqb, Wkb, Wvb, (void*)Qh, (void*)Kh, (void*)Vh, 4096, 6144, 2048);

  transpose_v<<<dim3(32, 32, 2), 256, 0, stream>>>(Vh, Vt);

  attn_kernel<<<dim3(32, 16), 256, 0, stream>>>(Qh, Kh, Vt, Ob);

  gemm_bt<1><<<dim3(2048 / 128, 4096 / 128), 256, 0, stream>>>(
      Ob, Wob, nullptr, nullptr, (void*)out, nullptr, nullptr, 4096, 2048, 2048);
}